// Round 9
// baseline (9919.572 us; speedup 1.0000x reference)
//
#include <hip/hip_runtime.h>

typedef _Float16 f16;
typedef _Float16 f16x8 __attribute__((ext_vector_type(8)));
typedef _Float16 f16x4 __attribute__((ext_vector_type(4)));
typedef float f32x4 __attribute__((ext_vector_type(4)));

#define T_TOT 2048
#define BATCH 64
#define HID 256
#define G3 768
#define WS 32
#define NWIN 64
#define NRING 4
#define IPT 12288                   // f16 per timestep per lg: 3 gates x 256 j x 16 b
#define IPSLOT (WS * IPT)           // 393216 f16 per ring slot

#define NLOG2E -1.44269504088896f   // -log2(e): sigmoid pre-scale
#define P2LOG2E 2.88539008177793f   // +2*log2(e): tanh pre-scale

#define SPIN_BUDGET 20000000L       // bails instead of hanging the queue

#define SMEM_BYTES 65536            // worker As[128][256]; scan uses first 16 KB (h dbuf)

// flags (monotone single-writer counters), zero-initialized:
#define F_YPROG(lg)   (lg)                    // scan l: y windows produced
#define F_IPCONS(lg)  (24 + (lg))             // scan l: ip windows consumed
#define F_IPP(lg,q)   (48 + (lg)*4 + (q))     // worker q of layer l: ip produced
#define F_YC(lg,q)    (144 + (lg)*4 + (q))    // worker q of layer l+1: y consumed

__device__ __forceinline__ float fexp2(float x) { return __builtin_amdgcn_exp2f(x); }
__device__ __forceinline__ float frcp(float x) { return __builtin_amdgcn_rcpf(x); }

// opaque identity: makes a loaded value NON-rematerializable so the register
// allocator must keep it resident (VGPR or AGPR) instead of re-loading each use
__device__ __forceinline__ f16x8 opaque(f16x8 v) {
    f32x4 t = __builtin_bit_cast(f32x4, v);
    asm volatile("" : "+v"(t));
    return __builtin_bit_cast(f16x8, t);
}

__device__ __forceinline__ void st_rel(int* p, int v) {
    __hip_atomic_store(p, v, __ATOMIC_RELEASE, __HIP_MEMORY_SCOPE_AGENT);
}
__device__ __forceinline__ int ld_rlx(int* p) {
    return __hip_atomic_load(p, __ATOMIC_RELAXED, __HIP_MEMORY_SCOPE_AGENT);
}
__device__ __forceinline__ void wait_ge(int* f, int target, int tid, long& budget) {
    if (tid == 0) {
        while (ld_rlx(f) < target) {
            if (--budget < 0) break;
            __builtin_amdgcn_s_sleep(2);
        }
        __builtin_amdgcn_fence(__ATOMIC_ACQUIRE, "agent");
    }
    __syncthreads();
}
__device__ __forceinline__ void wait4_ge(int* f, int target, int tid, long& budget) {
    if (tid == 0) {
        #pragma unroll
        for (int q = 0; q < 4; ++q)
            while (ld_rlx(f + q) < target) {
                if (--budget < 0) break;
                __builtin_amdgcn_s_sleep(2);
            }
        __builtin_amdgcn_fence(__ATOMIC_ACQUIRE, "agent");
    }
    __syncthreads();
}
// barrier draining ONLY LDS ops; global loads/stores stay in flight
__device__ __forceinline__ void bar_lgkm() {
    asm volatile("s_waitcnt lgkmcnt(0)\n\ts_barrier" ::: "memory");
}

__global__ void cvt_f16(const float* __restrict__ s, f16* __restrict__ d, int n) {
    int i = (blockIdx.x * 256 + threadIdx.x) * 4;
    if (i + 3 < n) {
        f32x4 v = *(const f32x4*)(s + i);
        f16x4 o = { (f16)v[0], (f16)v[1], (f16)v[2], (f16)v[3] };
        *(f16x4*)(d + i) = o;
    }
}

// W_hh with gate pre-scale: rows<512 (r,z) * -log2e; rows>=512 (n) * 2log2e
__global__ void cvt_whh(const float* __restrict__ s, f16* __restrict__ d, int n) {
    int i = (blockIdx.x * 256 + threadIdx.x) * 4;
    if (i + 3 < n) {
        int row = (i >> 8) % G3;
        float sc = (row < 512) ? NLOG2E : P2LOG2E;
        f32x4 v = *(const f32x4*)(s + i);
        f16x4 o = { (f16)(v[0] * sc), (f16)(v[1] * sc), (f16)(v[2] * sc), (f16)(v[3] * sc) };
        *(f16x4*)(d + i) = o;
    }
}

// biasc[l][g] = scale_g * (b_ih + b_hh for r,z ; b_ih only for n)
__global__ void bias_prep(const float* __restrict__ bi, const float* __restrict__ bh,
                          float* __restrict__ o) {
    int i = blockIdx.x * 256 + threadIdx.x;
    if (i < 6 * G3) {
        int g = i % G3;
        float sc = (g < 512) ? NLOG2E : P2LOG2E;
        o[i] = sc * (bi[i] + (g < 512 ? bh[i] : 0.0f));
    }
}

// bhns[l][j] = 2log2e * b_hh[l][512+j]
__global__ void bhn_prep(const float* __restrict__ bh, float* __restrict__ o) {
    int l = blockIdx.x, j = threadIdx.x;
    o[l * 256 + j] = P2LOG2E * bh[l * G3 + 512 + j];
}

// ---------------- scan role: one block = (layer l, batch group g of 16), 4 waves ------
// 1 wave/SIMD (512-reg unified budget). Wave wv owns h-dims [64wv,64wv+64) x 3 gates:
// 12 accumulators x 8 kf = 96 MFMAs/step, full matrix pipe to itself.
//   kf 0..6 -> wf[12][7] = 336 regs, opaque-pinned (finally fits: 512-reg budget)
//   kf 7    -> per-step global loads (whh slice is L2-resident, 1.15 MB/XCD),
//              prefetched at step start under the MFMA phase (VMEM pipe, not LDS port)
// LDS = h double buffer only (16 KB): 8 b128 reads + 4 b64 writes per wave per step.
// h in LDS in FRAGMENT ORDER: FR(kgrp,b) = (kgrp*16+b)*8 f16, kgrp in [0,32).
__device__ void scan_role(const f16* __restrict__ ipring, f16* __restrict__ yring,
                          const f16* __restrict__ whh, const float* __restrict__ bhns,
                          const float* __restrict__ h0, float* __restrict__ out,
                          int* flags, char* smem, int l, int g, int tid) {
    f16* hb = (f16*)smem;                      // [2][4096] f16 = 16 KB
    const int wv = tid >> 6, lane = tid & 63;  // wv 0..3
    const int quad = lane >> 4, b = lane & 15;
    const int dbase = 64 * wv;                 // wave's h-dim base
    const int lg = l * 4 + g;
    long budget = SPIN_BUDGET;

    const f16* wbase = whh + (long)l * G3 * HID;
    // A-fragments: rows = gate*256 + dbase + ss*16 + b ; k = kf*32 + quad*8
    f16x8 wf[12][7];
    #pragma unroll
    for (int gate = 0; gate < 3; ++gate)
        #pragma unroll
        for (int ss = 0; ss < 4; ++ss) {
            const f16* wp = wbase + (gate * 256 + dbase + ss * 16 + b) * 256 + quad * 8;
            #pragma unroll
            for (int kf = 0; kf < 7; ++kf)
                wf[gate * 4 + ss][kf] = opaque(*(const f16x8*)(wp + kf * 32));
        }
    // kf7 base: per-step loads at p7 + gate*65536 + ss*4096 (f16 offsets)
    const f16* p7 = wbase + (dbase + b) * 256 + 7 * 32 + quad * 8;

    f32x4 bhn[4];
    #pragma unroll
    for (int ss = 0; ss < 4; ++ss)
        bhn[ss] = *(const f32x4*)(bhns + l * 256 + dbase + ss * 16 + quad * 4);

    {   // h0 -> buffer 0 in FR layout (256 threads x 2 cover 32 kgrp x 16 b)
        #pragma unroll
        for (int it = 0; it < 2; ++it) {
            int idx = it * 256 + tid;
            int kgrp = idx >> 4, bb = idx & 15;
            const float* hp = h0 + (long)(l * 64 + g * 16 + bb) * HID + kgrp * 8;
            f32x4 v0 = *(const f32x4*)hp;
            f32x4 v1 = *(const f32x4*)(hp + 4);
            f16x8 h8 = { (f16)v0[0], (f16)v0[1], (f16)v0[2], (f16)v0[3],
                         (f16)v1[0], (f16)v1[1], (f16)v1[2], (f16)v1[3] };
            *(f16x8*)(&hb[(kgrp * 16 + bb) * 8]) = h8;
        }
    }
    f16x4 hp_[4];                               // lane's own 16 h dims, register-resident
    #pragma unroll
    for (int ss = 0; ss < 4; ++ss) {
        f32x4 v = *(const f32x4*)(h0 + (long)(l * 64 + g * 16 + b) * HID
                                  + dbase + ss * 16 + quad * 4);
        hp_[ss] = (f16x4){ (f16)v[0], (f16)v[1], (f16)v[2], (f16)v[3] };
    }
    __syncthreads();

    // lane addressing constants
    // ip elem (t,gate,j,b) at ((gate*8 + (j>>5))*4 + ((j&15)>>2))*128 + b*8 + ((j>>4)&1)*4 + (j&3)
    // j = dbase + ss*16 + quad*4 + r -> f16x8 base (8wv+quad)*128 + b*8, +4096/gate, +512/sp
    const int lane_off = (8 * wv + quad) * 128 + b * 8;
    // h write: kgrp = 8wv + 2ss + (quad>>1), sub = (quad&1)*4; ss adds 256 f16
    const int hw0 = ((8 * wv + (quad >> 1)) * 16 + b) * 8 + (quad & 1) * 4;
    const int dimc = dbase + quad * 4;          // lane's output dim base (ss adds 16)

    for (int w = 0; w < NWIN; ++w) {
        if (l < 5 && w >= NRING)
            wait4_ge(flags + F_YC(lg, 0), w - NRING + 1, tid, budget);
        wait4_ge(flags + F_IPP(lg, 0), w + 1, tid, budget);
        const int slot = w & (NRING - 1);
        const f16* ipt = ipring + ((long)lg * NRING + slot) * IPSLOT + lane_off;
        f16* yc = yring + (((long)lg * NRING + slot) * 512 + b) * HID + dimc;
        f16x8 p[3][2];                          // prime t=0: [gate][sp]
        #pragma unroll
        for (int gate = 0; gate < 3; ++gate)
            #pragma unroll
            for (int sp = 0; sp < 2; ++sp)
                p[gate][sp] = *(const f16x8*)(ipt + gate * 4096 + sp * 512);
        for (int tp = 0; tp < WS; tp += 2) {
            #pragma unroll
            for (int u = 0; u < 2; ++u) {
                const int rdo = u * 4096;       // read h(t-1) from buffer u
                const int wro = (u ^ 1) * 4096; // write h(t) to buffer u^1
                // prefetch kf7 weights (global, L2-hot) under the MFMA phase
                f16x8 wk[12];
                #pragma unroll
                for (int gate = 0; gate < 3; ++gate)
                    #pragma unroll
                    for (int ss = 0; ss < 4; ++ss)
                        wk[gate * 4 + ss] =
                            *(const f16x8*)(p7 + gate * 65536 + ss * 4096);
                f32x4 acc[12];
                #pragma unroll
                for (int i = 0; i < 8; ++i) acc[i] = (f32x4){0.f, 0.f, 0.f, 0.f};
                #pragma unroll
                for (int ss = 0; ss < 4; ++ss) acc[8 + ss] = bhn[ss];
                __builtin_amdgcn_s_setprio(1);
                #pragma unroll
                for (int kk = 0; kk < 7; ++kk) {   // register-resident weights
                    f16x8 hf = *(const f16x8*)(&hb[rdo + ((kk * 4 + quad) * 16 + b) * 8]);
                    #pragma unroll
                    for (int i = 0; i < 12; ++i)
                        acc[i] = __builtin_amdgcn_mfma_f32_16x16x32_f16(
                            wf[i][kk], hf, acc[i], 0, 0, 0);
                }
                {   // kf 7: L2-resident weights prefetched above
                    f16x8 hf = *(const f16x8*)(&hb[rdo + ((28 + quad) * 16 + b) * 8]);
                    #pragma unroll
                    for (int i = 0; i < 12; ++i)
                        acc[i] = __builtin_amdgcn_mfma_f32_16x16x32_f16(
                            wk[i], hf, acc[i], 0, 0, 0);
                }
                __builtin_amdgcn_s_setprio(0);
                // activation (16 dims per lane)
                f16x4 hnew[4];
                #pragma unroll
                for (int ss = 0; ss < 4; ++ss) {
                    #pragma unroll
                    for (int r = 0; r < 4; ++r) {
                        float pr = (float)p[0][ss >> 1][(ss & 1) * 4 + r];
                        float pz = (float)p[1][ss >> 1][(ss & 1) * 4 + r];
                        float pn = (float)p[2][ss >> 1][(ss & 1) * 4 + r];
                        float rr = frcp(1.0f + fexp2(acc[ss][r] + pr));
                        float zz = frcp(1.0f + fexp2(acc[4 + ss][r] + pz));
                        float tt = frcp(1.0f + fexp2(pn + rr * acc[8 + ss][r]));
                        float nn = 1.0f - 2.0f * tt;
                        hnew[ss][r] = (f16)(nn + zz * ((float)hp_[ss][r] - nn));
                    }
                    hp_[ss] = hnew[ss];
                    *(f16x4*)(&hb[wro + hw0 + ss * 256]) = hnew[ss];
                }
                // prefetch t+1 (clamped); loads issue BEFORE y-store (vmcnt FIFO)
                if (tp + u + 1 < WS) ipt += IPT;
                #pragma unroll
                for (int gate = 0; gate < 3; ++gate)
                    #pragma unroll
                    for (int sp = 0; sp < 2; ++sp)
                        p[gate][sp] = *(const f16x8*)(ipt + gate * 4096 + sp * 512);
                if (l < 5) {
                    #pragma unroll
                    for (int ss = 0; ss < 4; ++ss)
                        *(f16x4*)(yc + ss * 16) = hnew[ss];
                }
                yc += 16 * HID;
                bar_lgkm();                     // LDS-only drain, 1 barrier/step
            }
        }
        __syncthreads();                        // full drain (vmcnt) before publish
        if (tid == 0) {
            st_rel(flags + F_IPCONS(lg), w + 1);
            if (l < 5) st_rel(flags + F_YPROG(lg), w + 1);
        }
    }
    {   // final h (buffer 0 after 2048 steps) -> out (f32)
        #pragma unroll
        for (int it = 0; it < 2; ++it) {
            int idx = it * 256 + tid;
            int kgrp = idx >> 4, bb = idx & 15;
            f16x8 h8 = *(const f16x8*)(&hb[(kgrp * 16 + bb) * 8]);
            float* op = out + (long)(l * 64 + g * 16 + bb) * HID + kgrp * 8;
            f32x4 v0 = { (float)h8[0], (float)h8[1], (float)h8[2], (float)h8[3] };
            f32x4 v1 = { (float)h8[4], (float)h8[5], (float)h8[6], (float)h8[7] };
            *(f32x4*)op = v0;
            *(f32x4*)(op + 4) = v1;
        }
    }
}

// -------- worker role: ip GEMM, 4 waves, one 128-row m-tile (q) per window ------------
// mi = wv picks the 32-row strip; each wave sweeps all 768 cols via 12 nt x 64 cols.
// Epilogue: pre-scale and scatter into the lane-fragment ip layout (see scan_role).
// Window row m = t2*16 + b; for fixed (ms,ns): t2 = q*8+2*mi+ms, b = quad*4+r.
template<int K>
__device__ void worker_role(const f16* __restrict__ src, bool is_x, int g,
                            const f16* __restrict__ Wl, const float* __restrict__ bias,
                            f16* __restrict__ dstb, int* flags,
                            int lay, int lg, int plg, int q,
                            char* smem, int tid) {
    f16* As = (f16*)smem;                      // [128][K]
    const int wv = tid >> 6, lane = tid & 63;
    const int quad = lane >> 4, l16 = lane & 15;
    const int mi = wv;                          // 0..3
    constexpr int CPR = K / 8;
    long budget = SPIN_BUDGET;

    for (int w = 0; w < NWIN; ++w) {
        if (lay > 0) wait_ge(flags + F_YPROG(plg), w + 1, tid, budget);
        if (w >= NRING) wait_ge(flags + F_IPCONS(lg), w - NRING + 1, tid, budget);
        const int slot = w & (NRING - 1);
        f16* dst = dstb + (long)slot * IPSLOT;
        #pragma unroll
        for (int it = 0; it < (128 * CPR) / 256; ++it) {
            int idx = it * 256 + tid;
            int row = idx / CPR, c8 = idx % CPR;
            int wr = q * 128 + row;
            long soff;
            if (is_x) soff = ((long)(w * WS + (wr >> 4)) * 64 + g * 16 + (wr & 15)) * K + c8 * 8;
            else      soff = ((long)slot * 512 + wr) * K + c8 * 8;
            f16x8 v = *(const f16x8*)(src + soff);
            *(f16x8*)(&As[row * K + (c8 ^ (row & 7)) * 8]) = v;
        }
        __syncthreads();
        for (int nt = 0; nt < 12; ++nt) {
            const int cbase = nt * 64;
            f16x8 bc[4], bn[4];
            #pragma unroll
            for (int ns = 0; ns < 4; ++ns)
                bc[ns] = *(const f16x8*)(Wl + (long)(cbase + ns * 16 + l16) * K + quad * 8);
            f32x4 acc[2][4];
            #pragma unroll
            for (int i = 0; i < 2; ++i)
                #pragma unroll
                for (int j = 0; j < 4; ++j) acc[i][j] = (f32x4){0.f, 0.f, 0.f, 0.f};
            #pragma unroll
            for (int kf = 0; kf < K / 32; ++kf) {
                if (kf + 1 < K / 32) {
                    #pragma unroll
                    for (int ns = 0; ns < 4; ++ns)
                        bn[ns] = *(const f16x8*)(Wl + (long)(cbase + ns * 16 + l16) * K
                                                 + (kf + 1) * 32 + quad * 8);
                }
                f16x8 af[2];
                #pragma unroll
                for (int ms = 0; ms < 2; ++ms) {
                    int row = 32 * mi + 16 * ms + l16;
                    int c8 = (kf * 4 + quad) ^ (row & 7);
                    af[ms] = *(const f16x8*)(&As[row * K + c8 * 8]);
                }
                #pragma unroll
                for (int ms = 0; ms < 2; ++ms)
                    #pragma unroll
                    for (int ns = 0; ns < 4; ++ns)
                        acc[ms][ns] = __builtin_amdgcn_mfma_f32_16x16x32_f16(
                            af[ms], bc[ns], acc[ms][ns], 0, 0, 0);
                #pragma unroll
                for (int ns = 0; ns < 4; ++ns) bc[ns] = bn[ns];
            }
            #pragma unroll
            for (int ns = 0; ns < 4; ++ns) {
                int col = cbase + ns * 16 + l16;
                float bv = bias[col];
                float sc = (col < 512) ? NLOG2E : P2LOG2E;
                // decompose col -> (gate, wv2, s2, quad2, r2) for fragment layout
                int gate = col >> 8, j = col & 255;
                int wv2 = j >> 5, rem = j & 31;
                int s2 = rem >> 4, q2 = (rem & 15) >> 2, r2 = rem & 3;
                #pragma unroll
                for (int ms = 0; ms < 2; ++ms) {
                    int t2 = q * 8 + 2 * mi + ms;
                    f16* dp = dst + t2 * IPT + ((gate * 8 + wv2) * 4 + q2) * 128
                            + s2 * 4 + r2;
                    #pragma unroll
                    for (int r = 0; r < 4; ++r)
                        dp[(quad * 4 + r) * 8] = (f16)(acc[ms][ns][r] * sc + bv);
                }
            }
        }
        __syncthreads();                        // drains ip stores + protects As WAR
        if (tid == 0) {
            st_rel(flags + F_IPP(lg, q), w + 1);
            if (lay > 0) st_rel(flags + F_YC(plg, q), w + 1);
        }
    }
}

// XCD-affine decode: bid = xcd + 8*j, 3 lg per XCD, 5 roles (1 scan + 4 workers) per lg.
// 256-thread blocks, 1 wave/SIMD -> 512-reg unified budget for the scan weight set.
__global__ __launch_bounds__(256, 1) __attribute__((amdgpu_waves_per_eu(1, 1)))
void gru_fused(
        const f16* __restrict__ xh, const f16* __restrict__ wih,
        const f16* __restrict__ whh, const float* __restrict__ biasc,
        const float* __restrict__ bhns, const float* __restrict__ h0,
        float* __restrict__ out, f16* __restrict__ yring, f16* __restrict__ ipring,
        int* flags) {
    __shared__ __align__(16) char smem[SMEM_BYTES];
    const int bid = blockIdx.x, tid = threadIdx.x;
    const int x = bid & 7, j = bid >> 3;
    const int lgrp = j / 5, role = j % 5;
    const int lg = lgrp * 8 + x;                // 0..23, same-XCD as its workers
    const int l = lg >> 2, g = lg & 3;
    if (role == 0) {
        scan_role(ipring, yring, whh, bhns, h0, out, flags, smem, l, g, tid);
    } else {
        const int q = role - 1;
        const float* bias = biasc + l * G3;
        f16* dstb = ipring + (long)lg * NRING * IPSLOT;
        if (l == 0) {
            worker_role<128>(xh, true, g, wih, bias, dstb, flags,
                             0, lg, 0, q, smem, tid);
        } else {
            int plg = (l - 1) * 4 + g;
            const f16* Wl = wih + 768 * 128 + (long)(l - 1) * G3 * HID;
            const f16* src = yring + (long)plg * NRING * 512 * HID;
            worker_role<256>(src, false, g, Wl, bias, dstb, flags,
                             l, lg, plg, q, smem, tid);
        }
    }
}

extern "C" void kernel_launch(void* const* d_in, const int* in_sizes, int n_in,
                              void* d_out, int out_size, void* d_ws, size_t ws_size,
                              hipStream_t stream) {
    const float* x     = (const float*)d_in[0];   // [2048,64,128]
    const float* h0    = (const float*)d_in[1];   // [6,64,256]
    const float* w_ih0 = (const float*)d_in[2];   // [768,128]
    const float* w_ihr = (const float*)d_in[3];   // [5,768,256]
    const float* w_hh  = (const float*)d_in[4];   // [6,768,256]
    const float* b_ih  = (const float*)d_in[5];   // [6,768]
    const float* b_hh  = (const float*)d_in[6];   // [6,768]
    float* out = (float*)d_out;                   // [6,64,256]

    char* p = (char*)d_ws;
    f16* xh      = (f16*)p;   p += (long)T_TOT * BATCH * 128 * 2;        // 33.5 MB
    f16* wih     = (f16*)p;   p += (long)(768 * 128 + 5 * 768 * 256) * 2;
    f16* whh     = (f16*)p;   p += (long)6 * 768 * 256 * 2;
    float* biasc = (float*)p; p += (long)6 * G3 * 4;
    float* bhns  = (float*)p; p += (long)6 * 256 * 4;
    f16* yring   = (f16*)p;   p += (long)20 * NRING * 512 * HID * 2;     // 21 MB
    f16* ipring  = (f16*)p;   p += (long)24 * NRING * IPSLOT * 2;        // 75.5 MB
    int* flags   = (int*)p;   p += 1024;

    hipMemsetAsync(flags, 0, 1024, stream);
    cvt_f16<<<16384, 256, 0, stream>>>(x, xh, T_TOT * BATCH * 128);
    cvt_f16<<<96, 256, 0, stream>>>(w_ih0, wih, 768 * 128);
    cvt_f16<<<960, 256, 0, stream>>>(w_ihr, wih + 768 * 128, 5 * 768 * 256);
    cvt_whh<<<1152, 256, 0, stream>>>(w_hh, whh, 6 * 768 * 256);
    bias_prep<<<18, 256, 0, stream>>>(b_ih, b_hh, biasc);
    bhn_prep<<<6, 256, 0, stream>>>(b_hh, bhns);

    gru_fused<<<120, 256, 0, stream>>>(xh, wih, whh, biasc, bhns, h0, out,
                                       yring, ipring, flags);
}